// Round 4
// baseline (30.667 us; speedup 1.0000x reference)
//
#include <hip/hip_runtime.h>
#include <math.h>

// B=256, C=500, D=256. wf layout [C][B][D]: row (c,b) = 1KB contiguous.
// One block per sample b (grid=256 -> 1 block/CU, single pass, no tail).
// 16 waves; wave w owns contiguous c-chunk [32w, 32w+32) (guard c<500).
// 4-deep row prefetch per wave (4KB in flight), 4 independent reduce chains.
// First wf loads issued BEFORE the BCE phase. No memset, no atomics.
#define BB 256
#define CC 500
#define DD 256
#define MARGIN 0.3f

__device__ __forceinline__ float rowmax4(float4 v) {
    return fmaxf(fmaxf(v.x, v.y), fmaxf(v.z, v.w));
}

__global__ __launch_bounds__(1024) void fused_loss_kernel(
    const float* __restrict__ logits,   // [B, C]
    const float* __restrict__ wf,       // [C, B, D]
    const int*   __restrict__ labels,   // [B, C]
    float*       __restrict__ out)      // [B]
{
    const int b    = blockIdx.x;
    const int tid  = threadIdx.x;
    const int w    = tid >> 6;          // wave 0..15
    const int lane = tid & 63;

    __shared__ float sflag[CC];         // 1.0f if label==0 else 0.0f
    __shared__ float wsum[16];

    const int    r0   = w << 5;                     // wave's base c (0,32,...,480)
    const size_t rs   = (size_t)BB * DD;            // stride between c rows (floats)
    const float* base = wf + ((size_t)r0 * BB + b) * DD + (lane << 2);

    // ---- start the wf stream immediately: 4 rows in flight ----
    // (r0+3 <= 483 < 500 for every wave, so these are always valid)
    float4 q0 = *reinterpret_cast<const float4*>(base);
    float4 q1 = *reinterpret_cast<const float4*>(base + rs);
    float4 q2 = *reinterpret_cast<const float4*>(base + 2 * rs);
    float4 q3 = *reinterpret_cast<const float4*>(base + 3 * rs);

    // ---- BCE + label flags while the first loads are in flight ----
    float acc = 0.0f;
    if (tid < CC) {
        const int   lab = labels[b * CC + tid];
        const float x   = logits[b * CC + tid];
        sflag[tid] = (lab == 0) ? 1.0f : 0.0f;
        // stable BCE: max(x,0) - x*y + log1p(exp(-|x|))
        acc = fmaxf(x, 0.0f) - x * (float)lab + log1pf(__expf(-fabsf(x)));
    }
    __syncthreads();

    // ---- rejection stream: 8 x (process 4 rows, prefetch next 4) ----
    #pragma unroll
    for (int i = 0; i < 32; i += 4) {
        const float4 c0 = q0, c1 = q1, c2 = q2, c3 = q3;
        const int rn = r0 + i + 4;
        if (i < 28 && rn < CC) {        // chunks are 4-aligned; CC%4==0 -> all-or-none
            q0 = *reinterpret_cast<const float4*>(base + (size_t)(i + 4) * rs);
            q1 = *reinterpret_cast<const float4*>(base + (size_t)(i + 5) * rs);
            q2 = *reinterpret_cast<const float4*>(base + (size_t)(i + 6) * rs);
            q3 = *reinterpret_cast<const float4*>(base + (size_t)(i + 7) * rs);
        }
        float m0 = rowmax4(c0), m1 = rowmax4(c1), m2 = rowmax4(c2), m3 = rowmax4(c3);
        #pragma unroll
        for (int off = 32; off > 0; off >>= 1) {    // 4 independent chains (ILP)
            m0 = fmaxf(m0, __shfl_xor(m0, off));
            m1 = fmaxf(m1, __shfl_xor(m1, off));
            m2 = fmaxf(m2, __shfl_xor(m2, off));
            m3 = fmaxf(m3, __shfl_xor(m3, off));
        }
        const int r = r0 + i;
        if (lane == 0 && r < CC) {      // whole 4-chunk valid or not (CC%4==0)
            acc += sflag[r]     * fmaxf(1.0f / (1.0f + __expf(-m0)) - MARGIN, 0.0f);
            acc += sflag[r + 1] * fmaxf(1.0f / (1.0f + __expf(-m1)) - MARGIN, 0.0f);
            acc += sflag[r + 2] * fmaxf(1.0f / (1.0f + __expf(-m2)) - MARGIN, 0.0f);
            acc += sflag[r + 3] * fmaxf(1.0f / (1.0f + __expf(-m3)) - MARGIN, 0.0f);
        }
    }

    // ---- block reduce -> single store ----
    #pragma unroll
    for (int off = 32; off > 0; off >>= 1)
        acc += __shfl_xor(acc, off);
    if (lane == 0) wsum[w] = acc;
    __syncthreads();
    if (tid < 64) {
        float v = (tid < 16) ? wsum[tid] : 0.0f;
        #pragma unroll
        for (int off = 8; off > 0; off >>= 1)
            v += __shfl_xor(v, off);
        if (tid == 0) out[b] = v;
    }
}

extern "C" void kernel_launch(void* const* d_in, const int* in_sizes, int n_in,
                              void* d_out, int out_size, void* d_ws, size_t ws_size,
                              hipStream_t stream) {
    const float* logits = (const float*)d_in[0];
    const float* wf     = (const float*)d_in[1];
    const int*   labels = (const int*)d_in[2];
    float*       out    = (float*)d_out;

    fused_loss_kernel<<<dim3(BB), dim3(1024), 0, stream>>>(logits, wf, labels, out);
}

// Round 5
// 30.056 us; speedup vs baseline: 1.0203x; 1.0203x over previous
//
#include <hip/hip_runtime.h>
#include <math.h>

// B=256, C=500, D=256. wf layout [C][B][D]: row (c,b) = 1KB contiguous.
// One block per sample b (grid=256 -> 1 block/CU, single pass, no tail).
// 16 waves; wave w owns STRIDED rows c = w, w+16, w+32, ... (R3's winning
// pattern), now with a 4-deep register-rotated prefetch pipeline
// (4KB in flight per wave = 64KB/CU). First loads issued before BCE.
// No memset, no atomics: block computes out[b] completely, one store.
#define BB 256
#define CC 500
#define DD 256
#define MARGIN 0.3f

__device__ __forceinline__ float rowmax4(float4 v) {
    return fmaxf(fmaxf(v.x, v.y), fmaxf(v.z, v.w));
}

__global__ __launch_bounds__(1024) void fused_loss_kernel(
    const float* __restrict__ logits,   // [B, C]
    const float* __restrict__ wf,       // [C, B, D]
    const int*   __restrict__ labels,   // [B, C]
    float*       __restrict__ out)      // [B]
{
    const int b    = blockIdx.x;
    const int tid  = threadIdx.x;
    const int w    = tid >> 6;          // wave 0..15
    const int lane = tid & 63;

    __shared__ float sflag[CC];         // 1.0f if label==0 else 0.0f
    __shared__ float wsum[16];

    // wave w's row j is c = w + 16*j, j = 0..31 (c<500: 32 rows for w<4, else 31)
    const size_t step = (size_t)16 * BB * DD;   // floats between consecutive rows
    const float* base = wf + ((size_t)w * BB + b) * DD + (lane << 2);

    // ---- start the stream immediately: 4 rows in flight (c=w..w+48, all <500)
    float4 q0 = *reinterpret_cast<const float4*>(base);
    float4 q1 = *reinterpret_cast<const float4*>(base + step);
    float4 q2 = *reinterpret_cast<const float4*>(base + 2 * step);
    float4 q3 = *reinterpret_cast<const float4*>(base + 3 * step);

    // ---- BCE + label flags while the first loads are in flight ----
    float acc = 0.0f;
    if (tid < CC) {
        const int   lab = labels[b * CC + tid];
        const float x   = logits[b * CC + tid];
        sflag[tid] = (lab == 0) ? 1.0f : 0.0f;
        // stable BCE: max(x,0) - x*y + log1p(exp(-|x|))
        acc = fmaxf(x, 0.0f) - x * (float)lab + log1pf(__expf(-fabsf(x)));
    }
    __syncthreads();

    // ---- rejection stream: rows j..j+3 in regs, prefetch j+4..j+7 ----
    #pragma unroll
    for (int j = 0; j < 32; j += 4) {
        const float4 c0 = q0, c1 = q1, c2 = q2, c3 = q3;
        if (j + 4 < 32) {               // prefetch next 4 rows (wave-uniform guards)
            if (w + 16 * (j + 4) < CC)
                q0 = *reinterpret_cast<const float4*>(base + (size_t)(j + 4) * step);
            if (w + 16 * (j + 5) < CC)
                q1 = *reinterpret_cast<const float4*>(base + (size_t)(j + 5) * step);
            if (w + 16 * (j + 6) < CC)
                q2 = *reinterpret_cast<const float4*>(base + (size_t)(j + 6) * step);
            if (w + 16 * (j + 7) < CC)
                q3 = *reinterpret_cast<const float4*>(base + (size_t)(j + 7) * step);
        }
        float m0 = rowmax4(c0), m1 = rowmax4(c1), m2 = rowmax4(c2), m3 = rowmax4(c3);
        #pragma unroll
        for (int off = 32; off > 0; off >>= 1) {    // 4 independent chains (ILP)
            m0 = fmaxf(m0, __shfl_xor(m0, off));
            m1 = fmaxf(m1, __shfl_xor(m1, off));
            m2 = fmaxf(m2, __shfl_xor(m2, off));
            m3 = fmaxf(m3, __shfl_xor(m3, off));
        }
        if (lane == 0) {
            const int c = w + 16 * j;
            if (c < CC)
                acc += sflag[c]      * fmaxf(1.0f / (1.0f + __expf(-m0)) - MARGIN, 0.0f);
            if (c + 16 < CC)
                acc += sflag[c + 16] * fmaxf(1.0f / (1.0f + __expf(-m1)) - MARGIN, 0.0f);
            if (c + 32 < CC)
                acc += sflag[c + 32] * fmaxf(1.0f / (1.0f + __expf(-m2)) - MARGIN, 0.0f);
            if (c + 48 < CC)
                acc += sflag[c + 48] * fmaxf(1.0f / (1.0f + __expf(-m3)) - MARGIN, 0.0f);
        }
    }

    // ---- block reduce -> single store ----
    #pragma unroll
    for (int off = 32; off > 0; off >>= 1)
        acc += __shfl_xor(acc, off);
    if (lane == 0) wsum[w] = acc;
    __syncthreads();
    if (tid < 64) {
        float v = (tid < 16) ? wsum[tid] : 0.0f;
        #pragma unroll
        for (int off = 8; off > 0; off >>= 1)
            v += __shfl_xor(v, off);
        if (tid == 0) out[b] = v;
    }
}

extern "C" void kernel_launch(void* const* d_in, const int* in_sizes, int n_in,
                              void* d_out, int out_size, void* d_ws, size_t ws_size,
                              hipStream_t stream) {
    const float* logits = (const float*)d_in[0];
    const float* wf     = (const float*)d_in[1];
    const int*   labels = (const int*)d_in[2];
    float*       out    = (float*)d_out;

    fused_loss_kernel<<<dim3(BB), dim3(1024), 0, stream>>>(logits, wf, labels, out);
}

// Round 6
// 18.526 us; speedup vs baseline: 1.6553x; 1.6224x over previous
//
#include <hip/hip_runtime.h>
#include <math.h>

// B=256, C=500, D=256. wf layout [C][B][D]: row (c,b) = 1KB contiguous.
// KEY INSIGHT: rejection term only needs rows where labels[b,c]==0 (~50%).
// Per block b: BCE pass over labels/logits -> ballot-compact the label==0
// c-indices into LDS (deterministic prefix, no atomics) -> 16 waves stream
// only those rows (depth-2 register pipeline). One store, no memset/atomics.
#define BB 256
#define CC 500
#define DD 256
#define MARGIN 0.3f

__device__ __forceinline__ float rowmax4(float4 v) {
    return fmaxf(fmaxf(v.x, v.y), fmaxf(v.z, v.w));
}

__global__ __launch_bounds__(1024) void fused_loss_kernel(
    const float* __restrict__ logits,   // [B, C]
    const float* __restrict__ wf,       // [C, B, D]
    const int*   __restrict__ labels,   // [B, C]
    float*       __restrict__ out)      // [B]
{
    const int b    = blockIdx.x;
    const int tid  = threadIdx.x;
    const int w    = tid >> 6;          // wave 0..15
    const int lane = tid & 63;

    __shared__ int   clist[CC];         // compacted c's with label==0
    __shared__ int   wcnt[16];          // per-wave selected count
    __shared__ float wsum[16];

    // ---- phase 1: BCE + selection mask (tid == c for tid < 500) ----
    float acc = 0.0f;
    bool  sel = false;
    if (tid < CC) {
        const int   lab = labels[b * CC + tid];
        const float x   = logits[b * CC + tid];
        sel = (lab == 0);
        // stable BCE: max(x,0) - x*y + log1p(exp(-|x|))
        acc = fmaxf(x, 0.0f) - x * (float)lab + log1pf(__expf(-fabsf(x)));
    }
    const unsigned long long mask = __ballot(sel);
    if (lane == 0) wcnt[w] = __popcll(mask);
    __syncthreads();

    int off = 0;
    for (int i = 0; i < w; ++i) off += wcnt[i];       // prefix over earlier waves
    int nsel = off;
    for (int i = w; i < 16; ++i) nsel += wcnt[i];     // total selected
    if (sel) {
        const int rank = __popcll(mask & ((1ULL << lane) - 1ULL));
        clist[off + rank] = tid;                      // deterministic position
    }
    __syncthreads();

    // ---- phase 2: stream ONLY selected rows; wave w takes j = w, w+16, ... ----
    {
        const size_t rs  = (size_t)BB * DD;           // floats between c rows
        const float* wfb = wf + (size_t)b * DD + (lane << 2);

        int j  = w;
        int c0 = (j      < nsel) ? clist[j]      : -1;   // wave-uniform
        int c1 = (j + 16 < nsel) ? clist[j + 16] : -1;
        float4 v0, v1;
        if (c0 >= 0) v0 = *reinterpret_cast<const float4*>(wfb + (size_t)c0 * rs);
        if (c1 >= 0) v1 = *reinterpret_cast<const float4*>(wfb + (size_t)c1 * rs);

        while (c0 >= 0) {
            const int c2 = (j + 32 < nsel) ? clist[j + 32] : -1;
            float4 vn;
            if (c2 >= 0)                               // prefetch 2 ahead
                vn = *reinterpret_cast<const float4*>(wfb + (size_t)c2 * rs);

            float m = rowmax4(v0);
            #pragma unroll
            for (int o = 32; o > 0; o >>= 1)
                m = fmaxf(m, __shfl_xor(m, o));
            if (lane == 0) {
                const float s = 1.0f / (1.0f + __expf(-m));   // sigmoid(row max)
                acc += fmaxf(s - MARGIN, 0.0f);               // label==0 guaranteed
            }

            v0 = v1; v1 = vn; c0 = c1; c1 = c2; j += 16;
        }
    }

    // ---- block reduce -> single store ----
    #pragma unroll
    for (int o = 32; o > 0; o >>= 1)
        acc += __shfl_xor(acc, o);
    if (lane == 0) wsum[w] = acc;
    __syncthreads();
    if (tid < 64) {
        float v = (tid < 16) ? wsum[tid] : 0.0f;
        #pragma unroll
        for (int o = 8; o > 0; o >>= 1)
            v += __shfl_xor(v, o);
        if (tid == 0) out[b] = v;
    }
}

extern "C" void kernel_launch(void* const* d_in, const int* in_sizes, int n_in,
                              void* d_out, int out_size, void* d_ws, size_t ws_size,
                              hipStream_t stream) {
    const float* logits = (const float*)d_in[0];
    const float* wf     = (const float*)d_in[1];
    const int*   labels = (const int*)d_in[2];
    float*       out    = (float*)d_out;

    fused_loss_kernel<<<dim3(BB), dim3(1024), 0, stream>>>(logits, wf, labels, out);
}